// Round 2
// baseline (636.390 us; speedup 1.0000x reference)
//
#include <hip/hip_runtime.h>
#include <stdint.h>

#define AS1 __attribute__((address_space(1)))
#define AS3 __attribute__((address_space(3)))

typedef __attribute__((ext_vector_type(8))) short bf16x8;
typedef __attribute__((ext_vector_type(16))) float f32x16;

// ---- helpers ----

__device__ inline unsigned short f2bf(float f) {
    uint32_t u = __float_as_uint(f);
    u += 0x7FFFu + ((u >> 16) & 1u);   // round-to-nearest-even
    return (unsigned short)(u >> 16);
}

// sign of e_a * e_b in Cl(4,1), metric [1,1,1,1,-1]
__device__ inline float gp_sign(int a, int b) {
    int s = __popc((a >> 1) & b) + __popc((a >> 2) & b) +
            __popc((a >> 3) & b) + __popc((a >> 4) & b);
    s += (a & b) >> 4;   // e4^2 = -1
    return (s & 1) ? -1.0f : 1.0f;
}

// ---- kernel 1 (fused prep): cast x -> bf16  AND  build W_bigT bf16 ----
// blocks [0, 8192):      cast x (fp32 [2048,8192]) -> xb
// blocks [8192, 40960):  WT[(o*32+k),(i*32+l)] = bf16( w[o,i,l^k] * sgn(l^k,l) )
__global__ __launch_bounds__(256) void prep_kernel(const float* __restrict__ x,
                                                   const float* __restrict__ w,
                                                   unsigned short* __restrict__ xb,
                                                   unsigned short* __restrict__ WT) {
    if (blockIdx.x < 8192) {
        size_t t = (size_t)blockIdx.x * 256 + threadIdx.x;   // 8 elems each
        size_t base = t * 8;
        const float4* xp = (const float4*)(x + base);
        float4 a = xp[0], b = xp[1];
        union { unsigned short s[8]; uint4 v; } r;
        r.s[0] = f2bf(a.x); r.s[1] = f2bf(a.y); r.s[2] = f2bf(a.z); r.s[3] = f2bf(a.w);
        r.s[4] = f2bf(b.x); r.s[5] = f2bf(b.y); r.s[6] = f2bf(b.z); r.s[7] = f2bf(b.w);
        *((uint4*)(xb + base)) = r.v;
    } else {
        unsigned t = (blockIdx.x - 8192) * 256 + threadIdx.x;  // 8 elems each
        unsigned col8 = t & 1023;     // 16B chunk within row: covers (i, l0..l0+7)
        unsigned c = t >> 10;         // row index = o*32+k, 8192 rows
        unsigned k = c & 31;
        unsigned o = c >> 5;
        unsigned i = col8 >> 2;
        unsigned l0 = (col8 & 3) << 3;
        const float* wrow = w + ((size_t)o * 256 + i) * 32;
        union { unsigned short s[8]; uint4 v; } r;
#pragma unroll
        for (int u = 0; u < 8; ++u) {
            int l = (int)l0 + u;
            int j = l ^ (int)k;
            r.s[u] = f2bf(wrow[j] * gp_sign(j, l));
        }
        *((uint4*)(WT + (size_t)c * 8192 + (size_t)col8 * 8)) = r.v;
    }
}

// ---- kernel 2: GEMM C[2048,8192] = A * B^T (bf16 in, fp32 out) + fused 32-group L2 norm
// 128x128 tile, BK=32, 4 waves (2x2 of 64x64 each), 32x32x16 MFMA, 2x2 frags/wave.
// LDS chunk swizzle: logical 16B chunk (m,q) stored at slot (m, q ^ (m&3)); the
// permutation is applied to the GLOBAL source chunk at staging time so the LDS
// destination stays lane-contiguous (global_load_lds requirement).
__global__ __launch_bounds__(256) void gemm_kernel(const unsigned short* __restrict__ A,
                                                   const unsigned short* __restrict__ B,
                                                   float* __restrict__ C) {
    const int N = 8192, K = 8192;
    __shared__ alignas(16) unsigned short As[128 * 32];
    __shared__ alignas(16) unsigned short Bs[128 * 32];

    int tid = threadIdx.x;
    int wid = tid >> 6, lane = tid & 63;
    int row0 = blockIdx.x * 128;   // M panels (16)
    int col0 = blockIdx.y * 128;   // N panels (64)
    int wr = (wid >> 1) * 64, wc = (wid & 1) * 64;
    int lm = lane & 31, half = lane >> 5;
    int r3 = lm & 3;               // = row&3 for all frag rows this lane reads

    f32x16 acc[2][2];
#pragma unroll
    for (int ti = 0; ti < 2; ++ti)
#pragma unroll
        for (int tj = 0; tj < 2; ++tj)
            acc[ti][tj] = (f32x16)(0.f);

    for (int k0 = 0; k0 < K; k0 += 32) {
        // stage 128x32 bf16 tiles of A and B; swizzled global source chunk
#pragma unroll
        for (int p = 0; p < 2; ++p) {
            int c = p * 256 + tid;                 // LDS slot id 0..511
            int m = c >> 2;                        // tile row
            int off = ((c & 3) ^ (m & 3)) * 8;     // swizzled bf16 offset within row
            const unsigned short* ga = A + (size_t)(row0 + m) * K + k0 + off;
            const unsigned short* gb = B + (size_t)(col0 + m) * K + k0 + off;
            unsigned short* la = &As[(size_t)(p * 256 + wid * 64) * 8];  // wave-uniform base
            unsigned short* lb = &Bs[(size_t)(p * 256 + wid * 64) * 8];
            __builtin_amdgcn_global_load_lds((const AS1 void*)ga, (AS3 void*)la, 16, 0, 0);
            __builtin_amdgcn_global_load_lds((const AS1 void*)gb, (AS3 void*)lb, 16, 0, 0);
        }
        __syncthreads();

        // frag loads: logical chunk (ks*2 + half), physical = logical ^ (row&3)
        bf16x8 af[2][2], bfr[2][2];   // [kstep][tile]
#pragma unroll
        for (int ks = 0; ks < 2; ++ks) {
            int cl = ks * 2 + half;
#pragma unroll
            for (int t = 0; t < 2; ++t) {
                int rowA = wr + t * 32 + lm;
                af[ks][t] = *(const bf16x8*)&As[rowA * 32 + ((cl ^ r3) * 8)];
                int rowB = wc + t * 32 + lm;
                bfr[ks][t] = *(const bf16x8*)&Bs[rowB * 32 + ((cl ^ r3) * 8)];
            }
        }
#pragma unroll
        for (int ks = 0; ks < 2; ++ks)
#pragma unroll
            for (int ti = 0; ti < 2; ++ti)
#pragma unroll
                for (int tj = 0; tj < 2; ++tj)
                    acc[ti][tj] = __builtin_amdgcn_mfma_f32_32x32x16_bf16(
                        af[ks][ti], bfr[ks][tj], acc[ti][tj], 0, 0, 0);
        __syncthreads();
    }

    // Epilogue: C/D layout col=lane&31, row=(reg&3)+8*(reg>>2)+4*half.
    // Norm group = the 32 cols of one 32x32 tile -> shfl_xor reduce over lane bits 0..4.
#pragma unroll
    for (int ti = 0; ti < 2; ++ti)
#pragma unroll
        for (int tj = 0; tj < 2; ++tj) {
            f32x16 v = acc[ti][tj];
#pragma unroll
            for (int r = 0; r < 16; ++r) {
                float ss = v[r] * v[r];
                ss += __shfl_xor(ss, 1);
                ss += __shfl_xor(ss, 2);
                ss += __shfl_xor(ss, 4);
                ss += __shfl_xor(ss, 8);
                ss += __shfl_xor(ss, 16);
                float inv = rsqrtf(ss + 1e-6f);
                int row = row0 + wr + ti * 32 + (r & 3) + 8 * (r >> 2) + 4 * half;
                int col = col0 + wc + tj * 32 + lm;
                C[(size_t)row * N + col] = v[r] * inv;
            }
        }
}

extern "C" void kernel_launch(void* const* d_in, const int* in_sizes, int n_in,
                              void* d_out, int out_size, void* d_ws, size_t ws_size,
                              hipStream_t stream) {
    const float* x = (const float*)d_in[0];   // [4,512,256,32]
    const float* w = (const float*)d_in[1];   // [256,256,32]
    float* out = (float*)d_out;               // [4,512,256,32]

    unsigned short* xb = (unsigned short*)d_ws;                           // 33,554,432 B
    unsigned short* WT = (unsigned short*)((char*)d_ws + 33554432);       // 134,217,728 B

    hipLaunchKernelGGL(prep_kernel, dim3(40960),  dim3(256), 0, stream, x, w, xb, WT);
    hipLaunchKernelGGL(gemm_kernel, dim3(16, 64), dim3(256), 0, stream, xb, WT, out);
}

// Round 3
// 265.709 us; speedup vs baseline: 2.3951x; 2.3951x over previous
//
#include <hip/hip_runtime.h>
#include <stdint.h>

#define AS1 __attribute__((address_space(1)))
#define AS3 __attribute__((address_space(3)))

typedef __attribute__((ext_vector_type(8))) short bf16x8;
typedef __attribute__((ext_vector_type(4))) float f32x4;

// ================= Cl(4,1) ~= M4(C) isomorphism, built at compile time =================
// Generators (monomial 4x4 complex, entries i^ph):
//  E0=s1(x)I, E1=s2(x)I, E2=s3(x)s1, E3=s3(x)s2 (square +1); E4=i*s3(x)s3 (square -1).
// Blade A (5-bit mask) -> M_A = product of E_b over set bits, ascending (matches the
// reference's canonical-order blade convention). Each M_A is monomial: M_A[r, col[r]] = i^ph[r].

struct Mono { int col[4]; int ph[4]; };

constexpr Mono mono_mul(Mono A, Mono B) {
    Mono R{};
    for (int r = 0; r < 4; ++r) {
        int k = A.col[r];
        R.col[r] = B.col[k];
        R.ph[r] = (A.ph[r] + B.ph[k]) & 3;
    }
    return R;
}

constexpr Mono gen(int g) {
    Mono E{};
    for (int r = 0; r < 4; ++r) {
        int r1 = (r >> 1) & 1, r0 = r & 1;
        if (g == 0)      { E.col[r] = r ^ 2; E.ph[r] = 0; }
        else if (g == 1) { E.col[r] = r ^ 2; E.ph[r] = r1 ? 1 : 3; }
        else if (g == 2) { E.col[r] = r ^ 1; E.ph[r] = r1 ? 2 : 0; }
        else if (g == 3) { E.col[r] = r ^ 1; E.ph[r] = ((r1 ? 2 : 0) + (r0 ? 1 : 3)) & 3; }
        else             { E.col[r] = r;     E.ph[r] = (1 + (r1 ? 2 : 0) + (r0 ? 2 : 0)) & 3; }
    }
    return E;
}

struct Blades { Mono m[32]; };
constexpr Blades make_blades() {
    Blades B{};
    for (int A = 0; A < 32; ++A) {
        Mono M{};
        for (int r = 0; r < 4; ++r) { M.col[r] = r; M.ph[r] = 0; }
        for (int g = 0; g < 5; ++g)
            if ((A >> g) & 1) M = mono_mul(M, gen(g));
        B.m[A] = M;
    }
    return B;
}
constexpr Blades BL = make_blades();

// Forward table: matrix entry (row r, col c, rc=0:Re/1:Im) = sum of 4 signed blade coeffs.
struct FwdTab { int bl[4][4][2][4]; float sg[4][4][2][4]; };
constexpr FwdTab make_fwd() {
    FwdTab T{};
    int cnt[4][4][2] = {};
    for (int A = 0; A < 32; ++A)
        for (int r = 0; r < 4; ++r) {
            int c = BL.m[A].col[r], p = BL.m[A].ph[r];
            int rc = p & 1;
            int& n = cnt[r][c][rc];
            T.bl[r][c][rc][n] = A;
            T.sg[r][c][rc][n] = (p & 2) ? -1.f : 1.f;
            ++n;
        }
    return T;
}
constexpr FwdTab FT = make_fwd();

__device__ inline unsigned short f2bf(float f) {
    uint32_t u = __float_as_uint(f);
    u += 0x7FFFu + ((u >> 16) & 1u);
    return (unsigned short)(u >> 16);
}

// ---- kernel 1 (fused transforms) ----
// blocks [0,2048):    x[n,i,0..31] -> X̂ real rows: Xb[(n*4+b)][i*8 + c*2 + rc]  (bf16)
// blocks [2048,2304): w[o,i,0..31] -> Ŵ real-embed: Wr[(ra*1024+o*4+a)][i*8 + c*2 + rc]
__global__ __launch_bounds__(256) void xform_kernel(const float* __restrict__ x,
                                                    const float* __restrict__ w,
                                                    unsigned short* __restrict__ Xb,
                                                    unsigned short* __restrict__ Wr) {
    if (blockIdx.x < 2048) {
        int t = blockIdx.x * 256 + threadIdx.x;     // t = n*256 + i
        int i = t & 255, n = t >> 8;
        float v[32];
        const float4* xp = (const float4*)(x + (size_t)t * 32);
#pragma unroll
        for (int q = 0; q < 8; ++q) {
            float4 f = xp[q];
            v[q * 4 + 0] = f.x; v[q * 4 + 1] = f.y; v[q * 4 + 2] = f.z; v[q * 4 + 3] = f.w;
        }
#pragma unroll
        for (int b = 0; b < 4; ++b) {
            union { unsigned short s[8]; uint4 u; } r;
#pragma unroll
            for (int c = 0; c < 4; ++c)
#pragma unroll
                for (int rc = 0; rc < 2; ++rc) {
                    float s = 0.f;
#pragma unroll
                    for (int j = 0; j < 4; ++j)
                        s += FT.sg[c][b][rc][j] * v[FT.bl[c][b][rc][j]];
                    r.s[c * 2 + rc] = f2bf(s);
                }
            *((uint4*)(Xb + (size_t)(n * 4 + b) * 2048 + i * 8)) = r.u;
        }
    } else {
        int t = (blockIdx.x - 2048) * 256 + threadIdx.x;   // t = o*256 + i
        int i = t & 255, o = t >> 8;
        float v[32];
        const float4* wp = (const float4*)(w + (size_t)t * 32);
#pragma unroll
        for (int q = 0; q < 8; ++q) {
            float4 f = wp[q];
            v[q * 4 + 0] = f.x; v[q * 4 + 1] = f.y; v[q * 4 + 2] = f.z; v[q * 4 + 3] = f.w;
        }
        float Re[4][4], Im[4][4];
#pragma unroll
        for (int a = 0; a < 4; ++a)
#pragma unroll
            for (int c = 0; c < 4; ++c) {
                float sr = 0.f, si = 0.f;
#pragma unroll
                for (int j = 0; j < 4; ++j) {
                    sr += FT.sg[a][c][0][j] * v[FT.bl[a][c][0][j]];
                    si += FT.sg[a][c][1][j] * v[FT.bl[a][c][1][j]];
                }
                Re[a][c] = sr; Im[a][c] = si;
            }
#pragma unroll
        for (int ra = 0; ra < 2; ++ra)
#pragma unroll
            for (int a = 0; a < 4; ++a) {
                int m = ra * 1024 + o * 4 + a;
                union { unsigned short s[8]; uint4 u; } r;
#pragma unroll
                for (int c = 0; c < 4; ++c) {
                    float v0 = ra == 0 ? Re[a][c] : Im[a][c];
                    float v1 = ra == 0 ? -Im[a][c] : Re[a][c];
                    r.s[c * 2 + 0] = f2bf(v0);
                    r.s[c * 2 + 1] = f2bf(v1);
                }
                *((uint4*)(Wr + (size_t)m * 2048 + i * 8)) = r.u;
            }
    }
}

// ---- kernel 2: GEMM C[2048,8192] = Wr[2048,2048] * Xb[8192,2048]^T (bf16 in, fp32 out)
// round-1 structure: 128x128 tile, BK=32, 4 waves (2x2 of 64x64), 16x16x32 MFMA, 4x4/wave
__global__ __launch_bounds__(256) void gemm_kernel(const unsigned short* __restrict__ A,
                                                   const unsigned short* __restrict__ B,
                                                   float* __restrict__ C) {
    const int N = 8192, K = 2048;
    __shared__ alignas(16) unsigned short As[128 * 32];
    __shared__ alignas(16) unsigned short Bs[128 * 32];

    int tid = threadIdx.x;
    int wid = tid >> 6, lane = tid & 63;
    int row0 = blockIdx.y * 128;   // M panels (16)
    int col0 = blockIdx.x * 128;   // N panels (64)
    int wr = (wid >> 1) * 64, wc = (wid & 1) * 64;
    int lm = lane & 15, quad = lane >> 4;

    f32x4 acc[4][4];
#pragma unroll
    for (int ti = 0; ti < 4; ++ti)
#pragma unroll
        for (int tj = 0; tj < 4; ++tj)
            acc[ti][tj] = (f32x4){0.f, 0.f, 0.f, 0.f};

    for (int k0 = 0; k0 < K; k0 += 32) {
#pragma unroll
        for (int p = 0; p < 2; ++p) {
            int c = p * 256 + tid;
            int m = c >> 2;
            int off = (c & 3) * 8;
            const unsigned short* ga = A + (size_t)(row0 + m) * K + k0 + off;
            const unsigned short* gb = B + (size_t)(col0 + m) * K + k0 + off;
            unsigned short* la = &As[(size_t)(p * 256 + wid * 64) * 8];
            unsigned short* lb = &Bs[(size_t)(p * 256 + wid * 64) * 8];
            __builtin_amdgcn_global_load_lds((const AS1 void*)ga, (AS3 void*)la, 16, 0, 0);
            __builtin_amdgcn_global_load_lds((const AS1 void*)gb, (AS3 void*)lb, 16, 0, 0);
        }
        __syncthreads();

        bf16x8 af[4], bfr[4];
#pragma unroll
        for (int ti = 0; ti < 4; ++ti)
            af[ti] = *(const bf16x8*)&As[(wr + ti * 16 + lm) * 32 + quad * 8];
#pragma unroll
        for (int tj = 0; tj < 4; ++tj)
            bfr[tj] = *(const bf16x8*)&Bs[(wc + tj * 16 + lm) * 32 + quad * 8];
#pragma unroll
        for (int ti = 0; ti < 4; ++ti)
#pragma unroll
            for (int tj = 0; tj < 4; ++tj)
                acc[ti][tj] = __builtin_amdgcn_mfma_f32_16x16x32_bf16(af[ti], bfr[tj],
                                                                      acc[ti][tj], 0, 0, 0);
        __syncthreads();
    }

#pragma unroll
    for (int ti = 0; ti < 4; ++ti)
#pragma unroll
        for (int tj = 0; tj < 4; ++tj)
#pragma unroll
            for (int r = 0; r < 4; ++r) {
                int row = row0 + wr + ti * 16 + quad * 4 + r;
                int col = col0 + wc + tj * 16 + lm;
                C[(size_t)row * N + col] = acc[ti][tj][r];
            }
}

// ---- kernel 3: inverse transform + L2 normalize ----
// per (n,o): read C patch rows (ra*1024+o*4+a), cols n*4..+3; blade_A = 0.25*sum_a ±V;
// ||blades||^2 = ||V||^2/16 computed from xa directly; write out[n,o,0..31].
__global__ __launch_bounds__(256) void epi_kernel(const float* __restrict__ C,
                                                  float* __restrict__ out) {
    int tid = threadIdx.x;
    int nl = tid & 3, ol = tid >> 2;                 // block: 64 o x 4 n
    int o = (blockIdx.x & 3) * 64 + ol;
    int n = (blockIdx.x >> 2) * 4 + nl;              // grid 2048 = 4 x 512

    float V[32];   // idx = ra*16 + a*4 + b
#pragma unroll
    for (int ra = 0; ra < 2; ++ra)
#pragma unroll
        for (int a = 0; a < 4; ++a) {
            float4 f = *(const float4*)(C + (size_t)(ra * 1024 + o * 4 + a) * 8192 + n * 4);
            V[ra * 16 + a * 4 + 0] = f.x; V[ra * 16 + a * 4 + 1] = f.y;
            V[ra * 16 + a * 4 + 2] = f.z; V[ra * 16 + a * 4 + 3] = f.w;
        }
    float xa[32];
    float ss = 0.f;
#pragma unroll
    for (int A = 0; A < 32; ++A) {
        float s = 0.f;
#pragma unroll
        for (int a = 0; a < 4; ++a) {
            const int c = BL.m[A].col[a];
            const int p = BL.m[A].ph[a];
            float vv = V[(p & 1) * 16 + a * 4 + c];
            s += (p & 2) ? -vv : vv;
        }
        s *= 0.25f;
        xa[A] = s;
        ss += s * s;
    }
    float inv = rsqrtf(ss + 1e-6f);
    float4* op = (float4*)(out + ((size_t)n * 256 + o) * 32);
#pragma unroll
    for (int q = 0; q < 8; ++q) {
        float4 f;
        f.x = xa[q * 4 + 0] * inv; f.y = xa[q * 4 + 1] * inv;
        f.z = xa[q * 4 + 2] * inv; f.w = xa[q * 4 + 3] * inv;
        op[q] = f;
    }
}

extern "C" void kernel_launch(void* const* d_in, const int* in_sizes, int n_in,
                              void* d_out, int out_size, void* d_ws, size_t ws_size,
                              hipStream_t stream) {
    const float* x = (const float*)d_in[0];   // [4,512,256,32]
    const float* w = (const float*)d_in[1];   // [256,256,32]
    float* out = (float*)d_out;               // [4,512,256,32]

    unsigned short* Wr = (unsigned short*)d_ws;                             //  8,388,608 B
    unsigned short* Xb = (unsigned short*)((char*)d_ws + 8388608);          // 33,554,432 B
    float* Cbuf = (float*)((char*)d_ws + 41943040);                         // 67,108,864 B

    hipLaunchKernelGGL(xform_kernel, dim3(2304),   dim3(256), 0, stream, x, w, Xb, Wr);
    hipLaunchKernelGGL(gemm_kernel,  dim3(64, 16), dim3(256), 0, stream, Wr, Xb, Cbuf);
    hipLaunchKernelGGL(epi_kernel,   dim3(2048),   dim3(256), 0, stream, Cbuf, out);
}